// Round 2
// baseline (5080.991 us; speedup 1.0000x reference)
//
#include <hip/hip_runtime.h>
#include <math.h>

// 1/sqrt(1+1e-5) — eval BatchNorm with default stats
#define BNS 0.9999950000374997f

static inline int cdiv(int a, int b) { return (a + b - 1) / b; }

// ---------------- weight transposes ----------------
// regular conv: w[co][ci][27] (OIDHW) -> wT[ci][tap][co]
__global__ void k_tr_conv(const float* __restrict__ w, float* __restrict__ wT,
                          int CIN, int COUT) {
    int i = blockIdx.x * 256 + threadIdx.x;
    int total = CIN * COUT * 27;
    if (i >= total) return;
    int co = i % COUT;
    int tap = (i / COUT) % 27;
    int ci = i / (COUT * 27);
    wT[i] = w[(co * CIN + ci) * 27 + tap];
}

// conv_transpose: w[ci=32][co=32][64] (IODHW) -> wT[ci][tap=64][co=32]
__global__ void k_tr_convT(const float* __restrict__ w, float* __restrict__ wT) {
    int i = blockIdx.x * 256 + threadIdx.x;
    if (i >= 32 * 64 * 32) return;
    int co = i & 31;
    int tap = (i >> 5) & 63;
    int ci = i >> 11;
    wT[i] = w[(ci * 32 + co) * 64 + tap];
}

// ---------------- conv_transpose 3d: prev[n,32,16^3] -> out[32,34^3], relu(x*BNS)
// out[z] taps dilated-padded input at p = z + kz - 3, valid iff p even, 0 <= p/2 < 16.
__global__ __launch_bounds__(256) void k_convT(const float* __restrict__ prev,
                                               const float* __restrict__ wT,
                                               float* __restrict__ out, int nbase) {
    int n = blockIdx.y;            // local (chunk) index
    int ng = nbase + n;            // global block index
    int s = blockIdx.x * 256 + threadIdx.x;
    if (s >= 34 * 34 * 34) return;
    int z = s / (34 * 34);
    int r = s % (34 * 34);
    int y = r / 34;
    int x = r % 34;

    int kz0 = 1 - (z & 1); int izb = (z + kz0 - 3) >> 1;
    int ky0 = 1 - (y & 1); int iyb = (y + ky0 - 3) >> 1;
    int kx0 = 1 - (x & 1); int ixb = (x + kx0 - 3) >> 1;

    int offs[8];
    int widx[8];
    bool val[8];
    #pragma unroll
    for (int cz = 0; cz < 2; ++cz) {
        int iz = izb + cz; int kz = kz0 + 2 * cz;
        bool vz = (iz >= 0) && (iz < 16);
        #pragma unroll
        for (int cy = 0; cy < 2; ++cy) {
            int iy = iyb + cy; int ky = ky0 + 2 * cy;
            bool vy = (iy >= 0) && (iy < 16);
            #pragma unroll
            for (int cx = 0; cx < 2; ++cx) {
                int ix = ixb + cx; int kx = kx0 + 2 * cx;
                bool vx = (ix >= 0) && (ix < 16);
                int c = (cz * 2 + cy) * 2 + cx;
                val[c] = vz && vy && vx;
                offs[c] = (iz * 16 + iy) * 16 + ix;
                widx[c] = ((kz * 4 + ky) * 4 + kx) * 32;
            }
        }
    }

    float acc[32];
    #pragma unroll
    for (int c = 0; c < 32; ++c) acc[c] = 0.f;

    const float* pn = prev + (size_t)ng * 32 * 4096;
    for (int ci = 0; ci < 32; ++ci) {
        const float* pc = pn + ci * 4096;
        const float* wci = wT + ci * 64 * 32;
        #pragma unroll
        for (int c = 0; c < 8; ++c) {
            if (!val[c]) continue;
            float v = pc[offs[c]];
            const float* wp = wci + widx[c];
            #pragma unroll
            for (int co = 0; co < 32; ++co) acc[co] = fmaf(v, wp[co], acc[co]);
        }
    }

    float* o = out + (size_t)n * 32 * 39304 + s;
    #pragma unroll
    for (int co = 0; co < 32; ++co) {
        float v = acc[co] * BNS;
        o[(size_t)co * 39304] = v > 0.f ? v : 0.f;
    }
}

// ---------------- ts1: carve tsdf block ng (32^3 of 96^3), replicate-pad-2, conv 3^3 1->16, relu(x*BNS)
__global__ __launch_bounds__(256) void k_ts1(const float* __restrict__ tsdf,
                                             const float* __restrict__ wT,
                                             float* __restrict__ out, int nbase) {
    int n = blockIdx.y;
    int ng = nbase + n;
    int a1 = ng / 9, b1 = (ng / 3) % 3, c1 = ng % 3;
    int s = blockIdx.x * 256 + threadIdx.x;
    if (s >= 39304) return;
    int z = s / (34 * 34);
    int r = s % (34 * 34);
    int y = r / 34;
    int x = r % 34;

    int base = (a1 * 32 * 96 + b1 * 32) * 96 + c1 * 32;
    int offs[27];
    #pragma unroll
    for (int kz = 0; kz < 3; ++kz) {
        int zz = z + kz - 2; zz = zz < 0 ? 0 : (zz > 31 ? 31 : zz);
        #pragma unroll
        for (int ky = 0; ky < 3; ++ky) {
            int yy = y + ky - 2; yy = yy < 0 ? 0 : (yy > 31 ? 31 : yy);
            #pragma unroll
            for (int kx = 0; kx < 3; ++kx) {
                int xx = x + kx - 2; xx = xx < 0 ? 0 : (xx > 31 ? 31 : xx);
                offs[(kz * 3 + ky) * 3 + kx] = zz * 9216 + yy * 96 + xx;
            }
        }
    }

    float acc[16];
    #pragma unroll
    for (int c = 0; c < 16; ++c) acc[c] = 0.f;

    const float* p = tsdf + base;
    #pragma unroll
    for (int t = 0; t < 27; ++t) {
        float v = p[offs[t]];
        const float* wp = wT + t * 16;
        #pragma unroll
        for (int co = 0; co < 16; ++co) acc[co] = fmaf(v, wp[co], acc[co]);
    }

    float* o = out + (size_t)n * 16 * 39304 + s;
    #pragma unroll
    for (int co = 0; co < 16; ++co) {
        float v = acc[co] * BNS;
        o[(size_t)co * 39304] = v > 0.f ? v : 0.f;
    }
}

// ---------------- generic 3^3 conv, NCDHW, per-thread acc over all Cout
// PAD=true: replicate-pad-2 then VALID (OUTD=IND+2); PAD=false: VALID (OUTD=IND-2)
template <int CIN, int COUT, int IND, int OUTD, bool PAD, bool RELU>
__global__ __launch_bounds__(256) void k_conv3(const float* __restrict__ in,
                                               const float* __restrict__ wT,
                                               float* __restrict__ out,
                                               int in_ctot, int in_coff,
                                               int out_ctot, int out_coff) {
    constexpr int IN3 = IND * IND * IND;
    constexpr int OD3 = OUTD * OUTD * OUTD;
    int n = blockIdx.y;
    int s = blockIdx.x * 256 + threadIdx.x;
    if (s >= OD3) return;
    int z = s / (OUTD * OUTD);
    int r = s % (OUTD * OUTD);
    int y = r / OUTD;
    int x = r % OUTD;

    int offs[27];
    #pragma unroll
    for (int kz = 0; kz < 3; ++kz) {
        int zz = PAD ? z + kz - 2 : z + kz;
        if (PAD) zz = zz < 0 ? 0 : (zz > IND - 1 ? IND - 1 : zz);
        #pragma unroll
        for (int ky = 0; ky < 3; ++ky) {
            int yy = PAD ? y + ky - 2 : y + ky;
            if (PAD) yy = yy < 0 ? 0 : (yy > IND - 1 ? IND - 1 : yy);
            #pragma unroll
            for (int kx = 0; kx < 3; ++kx) {
                int xx = PAD ? x + kx - 2 : x + kx;
                if (PAD) xx = xx < 0 ? 0 : (xx > IND - 1 ? IND - 1 : xx);
                offs[(kz * 3 + ky) * 3 + kx] = (zz * IND + yy) * IND + xx;
            }
        }
    }

    float acc[COUT];
    #pragma unroll
    for (int c = 0; c < COUT; ++c) acc[c] = 0.f;

    const float* inN = in + ((size_t)n * in_ctot + in_coff) * IN3;
    for (int ci = 0; ci < CIN; ++ci) {
        const float* pc = inN + (size_t)ci * IN3;
        const float* wci = wT + ci * 27 * COUT;
        #pragma unroll
        for (int t = 0; t < 27; ++t) {
            float v = pc[offs[t]];
            const float* wp = wci + t * COUT;
            #pragma unroll
            for (int co = 0; co < COUT; ++co) acc[co] = fmaf(v, wp[co], acc[co]);
        }
    }

    float* o = out + ((size_t)n * out_ctot + out_coff) * OD3 + s;
    #pragma unroll
    for (int co = 0; co < COUT; ++co) {
        float v = acc[co] * BNS;
        if (RELU) v = v > 0.f ? v : 0.f;
        o[(size_t)co * OD3] = v;
    }
}

// ---------------- maxpool 3x3x3 stride 3: chunk bufA [ncnt,16,30^3] -> P1 global [27,16,10^3]
__global__ __launch_bounds__(256) void k_pool3(const float* __restrict__ in,
                                               float* __restrict__ out,
                                               int nbase, int ncnt) {
    int i = blockIdx.x * 256 + threadIdx.x;
    if (i >= ncnt * 16 * 1000) return;
    int x = i % 10;
    int y = (i / 10) % 10;
    int z = (i / 100) % 10;
    int nc = i / 1000;  // local n*16+c
    const float* p = in + (size_t)nc * 27000;
    float m = -INFINITY;
    #pragma unroll
    for (int dz = 0; dz < 3; ++dz)
        #pragma unroll
        for (int dy = 0; dy < 3; ++dy)
            #pragma unroll
            for (int dx = 0; dx < 3; ++dx)
                m = fmaxf(m, p[((3 * z + dz) * 30 + 3 * y + dy) * 30 + 3 * x + dx]);
    out[((size_t)nbase * 16 + nc) * 1000 + (z * 100 + y * 10 + x)] = m;
}

// ---------------- maxpool4 + flatten + linear + softmax + threshold
// in: [27,8,8,8,8]; out: pred[27*3] then mixed[27] (as 0/1 floats)
__global__ __launch_bounds__(64) void k_final(const float* __restrict__ p2,
                                              const float* __restrict__ wlin,
                                              const float* __restrict__ blin,
                                              float* __restrict__ dout) {
    int n = blockIdx.x;
    int t = threadIdx.x;  // 64 = (c, dz, dy, dx)
    int c = t >> 3, dz = (t >> 2) & 1, dy = (t >> 1) & 1, dx = t & 1;
    const float* p = p2 + ((size_t)n * 8 + c) * 512;
    float m = -INFINITY;
    #pragma unroll
    for (int iz = 0; iz < 4; ++iz)
        #pragma unroll
        for (int iy = 0; iy < 4; ++iy)
            #pragma unroll
            for (int ix = 0; ix < 4; ++ix)
                m = fmaxf(m, p[((dz * 4 + iz) * 8 + dy * 4 + iy) * 8 + dx * 4 + ix]);
    __shared__ float h[64];
    __shared__ float lg[3];
    h[t] = m;
    __syncthreads();
    if (t < 3) {
        float acc = blin[t];
        for (int k = 0; k < 64; ++k) acc += h[k] * wlin[t * 64 + k];
        lg[t] = acc;
    }
    __syncthreads();
    if (t == 0) {
        float mx = fmaxf(fmaxf(lg[0], lg[1]), lg[2]);
        float e0 = expf(lg[0] - mx), e1 = expf(lg[1] - mx), e2 = expf(lg[2] - mx);
        float inv = 1.f / (e0 + e1 + e2);
        float p0 = e0 * inv, p1 = e1 * inv, p2v = e2 * inv;
        dout[n * 3 + 0] = p0;
        dout[n * 3 + 1] = p1;
        dout[n * 3 + 2] = p2v;
        dout[81 + n] = p2v > 0.1f ? 1.0f : 0.0f;
    }
}

extern "C" void kernel_launch(void* const* d_in, const int* in_sizes, int n_in,
                              void* d_out, int out_size, void* d_ws, size_t ws_size,
                              hipStream_t stream) {
    const float* tsdf  = (const float*)d_in[0];
    const float* prev  = (const float*)d_in[1];
    const float* w_upt = (const float*)d_in[2];
    const float* w_upc = (const float*)d_in[3];
    const float* w_ts1 = (const float*)d_in[4];
    const float* w_ts2 = (const float*)d_in[5];
    const float* w_b1a = (const float*)d_in[6];
    const float* w_b1b = (const float*)d_in[7];
    const float* w_pa  = (const float*)d_in[8];
    const float* w_pb  = (const float*)d_in[9];
    const float* w_lin = (const float*)d_in[10];
    const float* b_lin = (const float*)d_in[11];
    float* dout = (float*)d_out;

    float* ws = (float*)d_ws;
    size_t off = 0;
    auto alloc = [&](size_t nel) {
        float* p = ws + off;
        off += (nel + 63) & ~(size_t)63;
        return p;
    };
    // fixed small buffers (full 27 blocks)
    float* P1     = alloc((size_t)27 * 16 * 1000);
    float* P2     = alloc((size_t)27 * 8 * 512);
    float* wT_upt = alloc(32 * 64 * 32);
    float* wT_upc = alloc(32 * 27 * 32);
    float* wT_ts1 = alloc(1 * 27 * 16);
    float* wT_ts2 = alloc(16 * 27 * 16);
    float* wT_b1a = alloc(48 * 27 * 32);
    float* wT_b1b = alloc(32 * 27 * 32);
    float* wT_pa  = alloc(32 * 27 * 16);
    float* wT_pb  = alloc(16 * 27 * 8);
    size_t fixed_floats = off;

    // chunked A (34^3 x 32ch) and C (32^3 x 48ch) buffers: pick largest NB <= 27 that fits
    const size_t perA = (size_t)32 * 39304 + 64;   // +64 for alignment padding
    const size_t perC = (size_t)48 * 32768 + 64;
    const size_t per_block = perA + perC;
    size_t avail = ws_size / 4 > fixed_floats ? ws_size / 4 - fixed_floats : 0;
    int NB = (int)(avail / per_block);
    if (NB > 27) NB = 27;
    if (NB < 1) NB = 1;  // last resort (needs ~14.3 MB of ws)

    float* bufA = alloc((size_t)NB * 32 * 39304);
    float* bufC = alloc((size_t)NB * 48 * 32768);

    // weight transposes (tiny, once)
    k_tr_convT<<<cdiv(32 * 64 * 32, 256), 256, 0, stream>>>(w_upt, wT_upt);
    k_tr_conv<<<cdiv(32 * 32 * 27, 256), 256, 0, stream>>>(w_upc, wT_upc, 32, 32);
    k_tr_conv<<<cdiv(1 * 16 * 27, 256), 256, 0, stream>>>(w_ts1, wT_ts1, 1, 16);
    k_tr_conv<<<cdiv(16 * 16 * 27, 256), 256, 0, stream>>>(w_ts2, wT_ts2, 16, 16);
    k_tr_conv<<<cdiv(48 * 32 * 27, 256), 256, 0, stream>>>(w_b1a, wT_b1a, 48, 32);
    k_tr_conv<<<cdiv(32 * 32 * 27, 256), 256, 0, stream>>>(w_b1b, wT_b1b, 32, 32);
    k_tr_conv<<<cdiv(32 * 16 * 27, 256), 256, 0, stream>>>(w_pa, wT_pa, 32, 16);
    k_tr_conv<<<cdiv(16 * 8 * 27, 256), 256, 0, stream>>>(w_pb, wT_pb, 16, 8);

    for (int n0 = 0; n0 < 27; n0 += NB) {
        int nc = 27 - n0 < NB ? 27 - n0 : NB;

        // prevs path: convT (relu*bns) -> up_c (bns) into bufC ch0..31
        k_convT<<<dim3(cdiv(39304, 256), nc), 256, 0, stream>>>(prev, wT_upt, bufA, n0);
        k_conv3<32, 32, 34, 32, false, false>
            <<<dim3(cdiv(32768, 256), nc), 256, 0, stream>>>(bufA, wT_upc, bufC, 32, 0, 48, 0);

        // tsdf path: ts1 (carve+pad+conv, relu*bns) -> ts2 (bns) into bufC ch32..47
        k_ts1<<<dim3(cdiv(39304, 256), nc), 256, 0, stream>>>(tsdf, wT_ts1, bufA, n0);
        k_conv3<16, 16, 34, 32, false, false>
            <<<dim3(cdiv(32768, 256), nc), 256, 0, stream>>>(bufA, wT_ts2, bufC, 16, 0, 48, 32);

        // fuse block: b1a (pad, relu*bns) -> b1b (bns) = feat into bufC ch0..31 (ctot=32)
        k_conv3<48, 32, 32, 34, true, true>
            <<<dim3(cdiv(39304, 256), nc), 256, 0, stream>>>(bufC, wT_b1a, bufA, 48, 0, 32, 0);
        k_conv3<32, 32, 34, 32, false, false>
            <<<dim3(cdiv(32768, 256), nc), 256, 0, stream>>>(bufA, wT_b1b, bufC, 32, 0, 32, 0);

        // pred conv a + pool3 into global P1
        k_conv3<32, 16, 32, 30, false, true>
            <<<dim3(cdiv(27000, 256), nc), 256, 0, stream>>>(bufC, wT_pa, bufA, 32, 0, 16, 0);
        k_pool3<<<cdiv(nc * 16 * 1000, 256), 256, 0, stream>>>(bufA, P1, n0, nc);
    }

    // tail: pb conv on pooled (global), pool4 + linear + softmax + threshold
    k_conv3<16, 8, 10, 8, false, true>
        <<<dim3(cdiv(512, 256), 27), 256, 0, stream>>>(P1, wT_pb, P2, 16, 0, 8, 0);
    k_final<<<27, 64, 0, stream>>>(P2, w_lin, b_lin, dout);
}

// Round 3
// 3470.836 us; speedup vs baseline: 1.4639x; 1.4639x over previous
//
#include <hip/hip_runtime.h>
#include <math.h>

// 1/sqrt(1+1e-5) — eval BatchNorm with default stats
#define BNS 0.9999950000374997f

static inline int cdiv(int a, int b) { return (a + b - 1) / b; }

// ---------------- weight transposes ----------------
// regular conv: w[co][ci][27] (OIDHW) -> wT[ci][tap][co]
__global__ void k_tr_conv(const float* __restrict__ w, float* __restrict__ wT,
                          int CIN, int COUT) {
    int i = blockIdx.x * 256 + threadIdx.x;
    int total = CIN * COUT * 27;
    if (i >= total) return;
    int co = i % COUT;
    int tap = (i / COUT) % 27;
    int ci = i / (COUT * 27);
    wT[i] = w[(co * CIN + ci) * 27 + tap];
}

// conv_transpose: w[ci=32][co=32][64] (IODHW) -> wT[ci][tap=64][co=32]
__global__ void k_tr_convT(const float* __restrict__ w, float* __restrict__ wT) {
    int i = blockIdx.x * 256 + threadIdx.x;
    if (i >= 32 * 64 * 32) return;
    int co = i & 31;
    int tap = (i >> 5) & 63;
    int ci = i >> 11;
    wT[i] = w[(ci * 32 + co) * 64 + tap];
}

// ---------------- conv_transpose 3d, parity-decomposed:
// prev[ng,32,16^3] -> out[n,32,34^3], epilogue relu(x*BNS).
// For output z with parity pz: taps kz = (1-pz)+2*cz, input iz = tz-1+cz (z=2*tz+pz).
// blockIdx.y = parity class q=(pz<<2)|(py<<1)|px  ->  weight addresses are wave-uniform
// (scalar loads), input loads coalesced along tx.
__global__ __launch_bounds__(256) void k_convT(const float* __restrict__ prev,
                                               const float* __restrict__ wT,
                                               float* __restrict__ out, int nbase) {
    int n = blockIdx.z;            // local (chunk) index
    int ng = nbase + n;            // global block index
    int q = blockIdx.y;
    int px = q & 1, py = (q >> 1) & 1, pz = q >> 2;
    int s = blockIdx.x * 256 + threadIdx.x;
    if (s >= 17 * 17 * 17) return;
    int tz = s / 289;
    int r = s % 289;
    int ty = r / 17;
    int tx = r % 17;

    // per-thread input offsets + masks for the 2x2x2 neighborhood (ci-invariant)
    int off[8];
    float msk[8];
    #pragma unroll
    for (int cz = 0; cz < 2; ++cz) {
        int iz = tz - 1 + cz;
        bool vz = (unsigned)iz < 16u;
        int izc = vz ? iz : 0;
        #pragma unroll
        for (int cy = 0; cy < 2; ++cy) {
            int iy = ty - 1 + cy;
            bool vy = (unsigned)iy < 16u;
            int iyc = vy ? iy : 0;
            #pragma unroll
            for (int cx = 0; cx < 2; ++cx) {
                int ix = tx - 1 + cx;
                bool vx = (unsigned)ix < 16u;
                int ixc = vx ? ix : 0;
                int c = (cz * 2 + cy) * 2 + cx;
                off[c] = (izc * 16 + iyc) * 16 + ixc;
                msk[c] = (vz && vy && vx) ? 1.f : 0.f;
            }
        }
    }

    int kz0 = 1 - pz, ky0 = 1 - py, kx0 = 1 - px;
    // wave-uniform weight row offsets for the 8 taps
    int wrow[8];
    #pragma unroll
    for (int cz = 0; cz < 2; ++cz)
        #pragma unroll
        for (int cy = 0; cy < 2; ++cy)
            #pragma unroll
            for (int cx = 0; cx < 2; ++cx)
                wrow[(cz * 2 + cy) * 2 + cx] =
                    (((kz0 + 2 * cz) * 4 + (ky0 + 2 * cy)) * 4 + (kx0 + 2 * cx)) * 32;

    float acc[32];
    #pragma unroll
    for (int co = 0; co < 32; ++co) acc[co] = 0.f;

    const float* pn = prev + (size_t)ng * 32 * 4096;
    for (int ci = 0; ci < 32; ++ci) {
        const float* pc = pn + ci * 4096;
        const float* wci = wT + ci * 64 * 32;
        #pragma unroll
        for (int c = 0; c < 8; ++c) {
            float v = pc[off[c]] * msk[c];
            const float* wp = wci + wrow[c];   // uniform -> s_load
            #pragma unroll
            for (int co = 0; co < 32; ++co) acc[co] = fmaf(v, wp[co], acc[co]);
        }
    }

    int z = 2 * tz + pz, y = 2 * ty + py, x = 2 * tx + px;
    float* o = out + (size_t)n * 32 * 39304 + ((z * 34 + y) * 34 + x);
    #pragma unroll
    for (int co = 0; co < 32; ++co) {
        float v = acc[co] * BNS;
        o[(size_t)co * 39304] = v > 0.f ? v : 0.f;
    }
}

// ---------------- ts1: carve tsdf block ng (32^3 of 96^3), replicate-pad-2, conv 3^3 1->16, relu(x*BNS)
__global__ __launch_bounds__(256) void k_ts1(const float* __restrict__ tsdf,
                                             const float* __restrict__ wT,
                                             float* __restrict__ out, int nbase) {
    int n = blockIdx.y;
    int ng = nbase + n;
    int a1 = ng / 9, b1 = (ng / 3) % 3, c1 = ng % 3;
    int s = blockIdx.x * 256 + threadIdx.x;
    if (s >= 39304) return;
    int z = s / (34 * 34);
    int r = s % (34 * 34);
    int y = r / 34;
    int x = r % 34;

    int base = (a1 * 32 * 96 + b1 * 32) * 96 + c1 * 32;
    int offs[27];
    #pragma unroll
    for (int kz = 0; kz < 3; ++kz) {
        int zz = z + kz - 2; zz = zz < 0 ? 0 : (zz > 31 ? 31 : zz);
        #pragma unroll
        for (int ky = 0; ky < 3; ++ky) {
            int yy = y + ky - 2; yy = yy < 0 ? 0 : (yy > 31 ? 31 : yy);
            #pragma unroll
            for (int kx = 0; kx < 3; ++kx) {
                int xx = x + kx - 2; xx = xx < 0 ? 0 : (xx > 31 ? 31 : xx);
                offs[(kz * 3 + ky) * 3 + kx] = zz * 9216 + yy * 96 + xx;
            }
        }
    }

    float acc[16];
    #pragma unroll
    for (int c = 0; c < 16; ++c) acc[c] = 0.f;

    const float* p = tsdf + base;
    #pragma unroll
    for (int t = 0; t < 27; ++t) {
        float v = p[offs[t]];
        const float* wp = wT + t * 16;
        #pragma unroll
        for (int co = 0; co < 16; ++co) acc[co] = fmaf(v, wp[co], acc[co]);
    }

    float* o = out + (size_t)n * 16 * 39304 + s;
    #pragma unroll
    for (int co = 0; co < 16; ++co) {
        float v = acc[co] * BNS;
        o[(size_t)co * 39304] = v > 0.f ? v : 0.f;
    }
}

// ---------------- generic 3^3 conv, NCDHW, per-thread acc over all Cout
// PAD=true: replicate-pad-2 then VALID (OUTD=IND+2); PAD=false: VALID (OUTD=IND-2)
template <int CIN, int COUT, int IND, int OUTD, bool PAD, bool RELU>
__global__ __launch_bounds__(256) void k_conv3(const float* __restrict__ in,
                                               const float* __restrict__ wT,
                                               float* __restrict__ out,
                                               int in_ctot, int in_coff,
                                               int out_ctot, int out_coff) {
    constexpr int IN3 = IND * IND * IND;
    constexpr int OD3 = OUTD * OUTD * OUTD;
    int n = blockIdx.y;
    int s = blockIdx.x * 256 + threadIdx.x;
    if (s >= OD3) return;
    int z = s / (OUTD * OUTD);
    int r = s % (OUTD * OUTD);
    int y = r / OUTD;
    int x = r % OUTD;

    int offs[27];
    #pragma unroll
    for (int kz = 0; kz < 3; ++kz) {
        int zz = PAD ? z + kz - 2 : z + kz;
        if (PAD) zz = zz < 0 ? 0 : (zz > IND - 1 ? IND - 1 : zz);
        #pragma unroll
        for (int ky = 0; ky < 3; ++ky) {
            int yy = PAD ? y + ky - 2 : y + ky;
            if (PAD) yy = yy < 0 ? 0 : (yy > IND - 1 ? IND - 1 : yy);
            #pragma unroll
            for (int kx = 0; kx < 3; ++kx) {
                int xx = PAD ? x + kx - 2 : x + kx;
                if (PAD) xx = xx < 0 ? 0 : (xx > IND - 1 ? IND - 1 : xx);
                offs[(kz * 3 + ky) * 3 + kx] = (zz * IND + yy) * IND + xx;
            }
        }
    }

    float acc[COUT];
    #pragma unroll
    for (int c = 0; c < COUT; ++c) acc[c] = 0.f;

    const float* inN = in + ((size_t)n * in_ctot + in_coff) * IN3;
    for (int ci = 0; ci < CIN; ++ci) {
        const float* pc = inN + (size_t)ci * IN3;
        const float* wci = wT + ci * 27 * COUT;
        #pragma unroll
        for (int t = 0; t < 27; ++t) {
            float v = pc[offs[t]];
            const float* wp = wci + t * COUT;
            #pragma unroll
            for (int co = 0; co < COUT; ++co) acc[co] = fmaf(v, wp[co], acc[co]);
        }
    }

    float* o = out + ((size_t)n * out_ctot + out_coff) * OD3 + s;
    #pragma unroll
    for (int co = 0; co < COUT; ++co) {
        float v = acc[co] * BNS;
        if (RELU) v = v > 0.f ? v : 0.f;
        o[(size_t)co * OD3] = v;
    }
}

// ---------------- maxpool 3x3x3 stride 3: chunk bufA [ncnt,16,30^3] -> P1 global [27,16,10^3]
__global__ __launch_bounds__(256) void k_pool3(const float* __restrict__ in,
                                               float* __restrict__ out,
                                               int nbase, int ncnt) {
    int i = blockIdx.x * 256 + threadIdx.x;
    if (i >= ncnt * 16 * 1000) return;
    int x = i % 10;
    int y = (i / 10) % 10;
    int z = (i / 100) % 10;
    int nc = i / 1000;  // local n*16+c
    const float* p = in + (size_t)nc * 27000;
    float m = -INFINITY;
    #pragma unroll
    for (int dz = 0; dz < 3; ++dz)
        #pragma unroll
        for (int dy = 0; dy < 3; ++dy)
            #pragma unroll
            for (int dx = 0; dx < 3; ++dx)
                m = fmaxf(m, p[((3 * z + dz) * 30 + 3 * y + dy) * 30 + 3 * x + dx]);
    out[((size_t)nbase * 16 + nc) * 1000 + (z * 100 + y * 10 + x)] = m;
}

// ---------------- maxpool4 + flatten + linear + softmax + threshold
// in: [27,8,8,8,8]; out: pred[27*3] then mixed[27] (as 0/1 floats)
__global__ __launch_bounds__(64) void k_final(const float* __restrict__ p2,
                                              const float* __restrict__ wlin,
                                              const float* __restrict__ blin,
                                              float* __restrict__ dout) {
    int n = blockIdx.x;
    int t = threadIdx.x;  // 64 = (c, dz, dy, dx)
    int c = t >> 3, dz = (t >> 2) & 1, dy = (t >> 1) & 1, dx = t & 1;
    const float* p = p2 + ((size_t)n * 8 + c) * 512;
    float m = -INFINITY;
    #pragma unroll
    for (int iz = 0; iz < 4; ++iz)
        #pragma unroll
        for (int iy = 0; iy < 4; ++iy)
            #pragma unroll
            for (int ix = 0; ix < 4; ++ix)
                m = fmaxf(m, p[((dz * 4 + iz) * 8 + dy * 4 + iy) * 8 + dx * 4 + ix]);
    __shared__ float h[64];
    __shared__ float lg[3];
    h[t] = m;
    __syncthreads();
    if (t < 3) {
        float acc = blin[t];
        for (int k = 0; k < 64; ++k) acc += h[k] * wlin[t * 64 + k];
        lg[t] = acc;
    }
    __syncthreads();
    if (t == 0) {
        float mx = fmaxf(fmaxf(lg[0], lg[1]), lg[2]);
        float e0 = expf(lg[0] - mx), e1 = expf(lg[1] - mx), e2 = expf(lg[2] - mx);
        float inv = 1.f / (e0 + e1 + e2);
        float p0 = e0 * inv, p1 = e1 * inv, p2v = e2 * inv;
        dout[n * 3 + 0] = p0;
        dout[n * 3 + 1] = p1;
        dout[n * 3 + 2] = p2v;
        dout[81 + n] = p2v > 0.1f ? 1.0f : 0.0f;
    }
}

extern "C" void kernel_launch(void* const* d_in, const int* in_sizes, int n_in,
                              void* d_out, int out_size, void* d_ws, size_t ws_size,
                              hipStream_t stream) {
    const float* tsdf  = (const float*)d_in[0];
    const float* prev  = (const float*)d_in[1];
    const float* w_upt = (const float*)d_in[2];
    const float* w_upc = (const float*)d_in[3];
    const float* w_ts1 = (const float*)d_in[4];
    const float* w_ts2 = (const float*)d_in[5];
    const float* w_b1a = (const float*)d_in[6];
    const float* w_b1b = (const float*)d_in[7];
    const float* w_pa  = (const float*)d_in[8];
    const float* w_pb  = (const float*)d_in[9];
    const float* w_lin = (const float*)d_in[10];
    const float* b_lin = (const float*)d_in[11];
    float* dout = (float*)d_out;

    float* ws = (float*)d_ws;
    size_t off = 0;
    auto alloc = [&](size_t nel) {
        float* p = ws + off;
        off += (nel + 63) & ~(size_t)63;
        return p;
    };
    // fixed small buffers (full 27 blocks)
    float* P1     = alloc((size_t)27 * 16 * 1000);
    float* P2     = alloc((size_t)27 * 8 * 512);
    float* wT_upt = alloc(32 * 64 * 32);
    float* wT_upc = alloc(32 * 27 * 32);
    float* wT_ts1 = alloc(1 * 27 * 16);
    float* wT_ts2 = alloc(16 * 27 * 16);
    float* wT_b1a = alloc(48 * 27 * 32);
    float* wT_b1b = alloc(32 * 27 * 32);
    float* wT_pa  = alloc(32 * 27 * 16);
    float* wT_pb  = alloc(16 * 27 * 8);
    size_t fixed_floats = off;

    // chunked A (34^3 x 32ch) and C (32^3 x 48ch) buffers: pick largest NB <= 27 that fits
    const size_t perA = (size_t)32 * 39304 + 64;   // +64 for alignment padding
    const size_t perC = (size_t)48 * 32768 + 64;
    const size_t per_block = perA + perC;
    size_t avail = ws_size / 4 > fixed_floats ? ws_size / 4 - fixed_floats : 0;
    int NB = (int)(avail / per_block);
    if (NB > 27) NB = 27;
    if (NB < 1) NB = 1;  // last resort (needs ~14.3 MB of ws)

    float* bufA = alloc((size_t)NB * 32 * 39304);
    float* bufC = alloc((size_t)NB * 48 * 32768);

    // weight transposes (tiny, once)
    k_tr_convT<<<cdiv(32 * 64 * 32, 256), 256, 0, stream>>>(w_upt, wT_upt);
    k_tr_conv<<<cdiv(32 * 32 * 27, 256), 256, 0, stream>>>(w_upc, wT_upc, 32, 32);
    k_tr_conv<<<cdiv(1 * 16 * 27, 256), 256, 0, stream>>>(w_ts1, wT_ts1, 1, 16);
    k_tr_conv<<<cdiv(16 * 16 * 27, 256), 256, 0, stream>>>(w_ts2, wT_ts2, 16, 16);
    k_tr_conv<<<cdiv(48 * 32 * 27, 256), 256, 0, stream>>>(w_b1a, wT_b1a, 48, 32);
    k_tr_conv<<<cdiv(32 * 32 * 27, 256), 256, 0, stream>>>(w_b1b, wT_b1b, 32, 32);
    k_tr_conv<<<cdiv(32 * 16 * 27, 256), 256, 0, stream>>>(w_pa, wT_pa, 32, 16);
    k_tr_conv<<<cdiv(16 * 8 * 27, 256), 256, 0, stream>>>(w_pb, wT_pb, 16, 8);

    for (int n0 = 0; n0 < 27; n0 += NB) {
        int nc = 27 - n0 < NB ? 27 - n0 : NB;

        // prevs path: convT (relu*bns, parity-decomposed) -> up_c (bns) into bufC ch0..31
        k_convT<<<dim3(cdiv(17 * 17 * 17, 256), 8, nc), 256, 0, stream>>>(prev, wT_upt, bufA, n0);
        k_conv3<32, 32, 34, 32, false, false>
            <<<dim3(cdiv(32768, 256), nc), 256, 0, stream>>>(bufA, wT_upc, bufC, 32, 0, 48, 0);

        // tsdf path: ts1 (carve+pad+conv, relu*bns) -> ts2 (bns) into bufC ch32..47
        k_ts1<<<dim3(cdiv(39304, 256), nc), 256, 0, stream>>>(tsdf, wT_ts1, bufA, n0);
        k_conv3<16, 16, 34, 32, false, false>
            <<<dim3(cdiv(32768, 256), nc), 256, 0, stream>>>(bufA, wT_ts2, bufC, 16, 0, 48, 32);

        // fuse block: b1a (pad, relu*bns) -> b1b (bns) = feat into bufC ch0..31 (ctot=32)
        k_conv3<48, 32, 32, 34, true, true>
            <<<dim3(cdiv(39304, 256), nc), 256, 0, stream>>>(bufC, wT_b1a, bufA, 48, 0, 32, 0);
        k_conv3<32, 32, 34, 32, false, false>
            <<<dim3(cdiv(32768, 256), nc), 256, 0, stream>>>(bufA, wT_b1b, bufC, 32, 0, 32, 0);

        // pred conv a + pool3 into global P1
        k_conv3<32, 16, 32, 30, false, true>
            <<<dim3(cdiv(27000, 256), nc), 256, 0, stream>>>(bufC, wT_pa, bufA, 32, 0, 16, 0);
        k_pool3<<<cdiv(nc * 16 * 1000, 256), 256, 0, stream>>>(bufA, P1, n0, nc);
    }

    // tail: pb conv on pooled (global), pool4 + linear + softmax + threshold
    k_conv3<16, 8, 10, 8, false, true>
        <<<dim3(cdiv(512, 256), 27), 256, 0, stream>>>(P1, wT_pb, P2, 16, 0, 8, 0);
    k_final<<<27, 64, 0, stream>>>(P2, w_lin, b_lin, dout);
}

// Round 4
// 1754.208 us; speedup vs baseline: 2.8965x; 1.9786x over previous
//
#include <hip/hip_runtime.h>
#include <math.h>

// 1/sqrt(1+1e-5) — eval BatchNorm with default stats
#define BNS 0.9999950000374997f

static inline int cdiv(int a, int b) { return (a + b - 1) / b; }

typedef short short8 __attribute__((ext_vector_type(8)));
typedef float f32x4 __attribute__((ext_vector_type(4)));
typedef unsigned int u32x4 __attribute__((ext_vector_type(4)));

__device__ __forceinline__ unsigned short f2bf(float f) {
    unsigned int u = __float_as_uint(f);
    u += 0x7fffu + ((u >> 16) & 1u);
    return (unsigned short)(u >> 16);
}

// ---------------- weight transposes ----------------
// regular conv (fp32 path): w[co][ci][27] (OIDHW) -> wT[ci][tap][co]
__global__ void k_tr_conv(const float* __restrict__ w, float* __restrict__ wT,
                          int CIN, int COUT) {
    int i = blockIdx.x * 256 + threadIdx.x;
    int total = CIN * COUT * 27;
    if (i >= total) return;
    int co = i % COUT;
    int tap = (i / COUT) % 27;
    int ci = i / (COUT * 27);
    wT[i] = w[(co * CIN + ci) * 27 + tap];
}

// conv_transpose: w[ci=32][co=32][64] (IODHW) -> wT[ci][tap=64][co=32]
__global__ void k_tr_convT(const float* __restrict__ w, float* __restrict__ wT) {
    int i = blockIdx.x * 256 + threadIdx.x;
    if (i >= 32 * 64 * 32) return;
    int co = i & 31;
    int tap = (i >> 5) & 63;
    int ci = i >> 11;
    wT[i] = w[(ci * 32 + co) * 64 + tap];
}

// MFMA conv weights: w[co][ci][27] fp32 -> Bt bf16 [chunk][tap][co][ci_local(32)], zero-padded ci
__global__ void k_trw(const float* __restrict__ w, unsigned short* __restrict__ Bt,
                      int CIN, int CHUNKS, int NCO) {
    int i = blockIdx.x * 256 + threadIdx.x;
    int total = CHUNKS * 27 * NCO * 32;
    if (i >= total) return;
    int cil = i & 31;
    int n = (i >> 5) % NCO;
    int t = (i / (32 * NCO)) % 27;
    int c = i / (32 * NCO * 27);
    int ci = c * 32 + cil;
    float v = (ci < CIN) ? w[(n * CIN + ci) * 27 + t] : 0.f;
    Bt[i] = f2bf(v);
}

// ---------------- conv_transpose 3d, parity-decomposed (fp32 vector path) ----------------
__global__ __launch_bounds__(256) void k_convT(const float* __restrict__ prev,
                                               const float* __restrict__ wT,
                                               float* __restrict__ out, int nbase) {
    int n = blockIdx.z;
    int ng = nbase + n;
    int q = blockIdx.y;
    int px = q & 1, py = (q >> 1) & 1, pz = q >> 2;
    int s = blockIdx.x * 256 + threadIdx.x;
    if (s >= 17 * 17 * 17) return;
    int tz = s / 289;
    int r = s % 289;
    int ty = r / 17;
    int tx = r % 17;

    int off[8];
    float msk[8];
    #pragma unroll
    for (int cz = 0; cz < 2; ++cz) {
        int iz = tz - 1 + cz;
        bool vz = (unsigned)iz < 16u;
        int izc = vz ? iz : 0;
        #pragma unroll
        for (int cy = 0; cy < 2; ++cy) {
            int iy = ty - 1 + cy;
            bool vy = (unsigned)iy < 16u;
            int iyc = vy ? iy : 0;
            #pragma unroll
            for (int cx = 0; cx < 2; ++cx) {
                int ix = tx - 1 + cx;
                bool vx = (unsigned)ix < 16u;
                int ixc = vx ? ix : 0;
                int c = (cz * 2 + cy) * 2 + cx;
                off[c] = (izc * 16 + iyc) * 16 + ixc;
                msk[c] = (vz && vy && vx) ? 1.f : 0.f;
            }
        }
    }

    int kz0 = 1 - pz, ky0 = 1 - py, kx0 = 1 - px;
    int wrow[8];
    #pragma unroll
    for (int cz = 0; cz < 2; ++cz)
        #pragma unroll
        for (int cy = 0; cy < 2; ++cy)
            #pragma unroll
            for (int cx = 0; cx < 2; ++cx)
                wrow[(cz * 2 + cy) * 2 + cx] =
                    (((kz0 + 2 * cz) * 4 + (ky0 + 2 * cy)) * 4 + (kx0 + 2 * cx)) * 32;

    float acc[32];
    #pragma unroll
    for (int co = 0; co < 32; ++co) acc[co] = 0.f;

    const float* pn = prev + (size_t)ng * 32 * 4096;
    for (int ci = 0; ci < 32; ++ci) {
        const float* pc = pn + ci * 4096;
        const float* wci = wT + ci * 64 * 32;
        #pragma unroll
        for (int c = 0; c < 8; ++c) {
            float v = pc[off[c]] * msk[c];
            const float* wp = wci + wrow[c];
            #pragma unroll
            for (int co = 0; co < 32; ++co) acc[co] = fmaf(v, wp[co], acc[co]);
        }
    }

    int z = 2 * tz + pz, y = 2 * ty + py, x = 2 * tx + px;
    float* o = out + (size_t)n * 32 * 39304 + ((z * 34 + y) * 34 + x);
    #pragma unroll
    for (int co = 0; co < 32; ++co) {
        float v = acc[co] * BNS;
        o[(size_t)co * 39304] = v > 0.f ? v : 0.f;
    }
}

// ---------------- ts1 (CIN=1, fp32 vector path) ----------------
__global__ __launch_bounds__(256) void k_ts1(const float* __restrict__ tsdf,
                                             const float* __restrict__ wT,
                                             float* __restrict__ out, int nbase) {
    int n = blockIdx.y;
    int ng = nbase + n;
    int a1 = ng / 9, b1 = (ng / 3) % 3, c1 = ng % 3;
    int s = blockIdx.x * 256 + threadIdx.x;
    if (s >= 39304) return;
    int z = s / (34 * 34);
    int r = s % (34 * 34);
    int y = r / 34;
    int x = r % 34;

    int base = (a1 * 32 * 96 + b1 * 32) * 96 + c1 * 32;
    int offs[27];
    #pragma unroll
    for (int kz = 0; kz < 3; ++kz) {
        int zz = z + kz - 2; zz = zz < 0 ? 0 : (zz > 31 ? 31 : zz);
        #pragma unroll
        for (int ky = 0; ky < 3; ++ky) {
            int yy = y + ky - 2; yy = yy < 0 ? 0 : (yy > 31 ? 31 : yy);
            #pragma unroll
            for (int kx = 0; kx < 3; ++kx) {
                int xx = x + kx - 2; xx = xx < 0 ? 0 : (xx > 31 ? 31 : xx);
                offs[(kz * 3 + ky) * 3 + kx] = zz * 9216 + yy * 96 + xx;
            }
        }
    }

    float acc[16];
    #pragma unroll
    for (int c = 0; c < 16; ++c) acc[c] = 0.f;

    const float* p = tsdf + base;
    #pragma unroll
    for (int t = 0; t < 27; ++t) {
        float v = p[offs[t]];
        const float* wp = wT + t * 16;
        #pragma unroll
        for (int co = 0; co < 16; ++co) acc[co] = fmaf(v, wp[co], acc[co]);
    }

    float* o = out + (size_t)n * 16 * 39304 + s;
    #pragma unroll
    for (int co = 0; co < 16; ++co) {
        float v = acc[co] * BNS;
        o[(size_t)co * 39304] = v > 0.f ? v : 0.f;
    }
}

// ---------------- MFMA implicit-GEMM 3^3 conv ----------------
// M = 2 output rows (one z, y0..y0+1, all x), N = NCO couts, K = ci (chunks of 32), taps serial.
// LDS: A-tile [p = (dz*4+dy)*XE+ix][ci(32)] bf16, 64B rows, 16B slots XOR-swizzled by (p>>1)&3.
// A-frag: lane holds A[m = l&15][k = g*8+e] as ds_read_b128; B-frag from global bf16
// Bt[(c*27+t)*NCO + n][32]: lane reads 8 ci at n = l&15. k-slot (g,e) bijection is applied
// identically on A and B, so the result is independent of the HW's (g,e)->k ordering.
// C/D: col(n) = lane&15, row(m) = (lane>>4)*4 + reg  [HW-verified mapping].
template <int CIN, int CHUNKS, int IND, int OUTD, bool PAD, bool RELU, int NCO>
__global__ __launch_bounds__((((2 * OUTD + 15) / 16) * 64)) void
k_cmfma(const float* __restrict__ in, const unsigned short* __restrict__ Bt,
        float* __restrict__ out, int in_ctot, int in_coff, int out_ctot, int out_coff) {
    constexpr int XE = OUTD + 2;       // staged x extent
    constexpr int S = 12 * XE;         // 3 z * 4 y * XE spatial positions
    constexpr int MT = 2 * OUTD;       // M tile
    constexpr int W = (MT + 15) / 16;  // waves
    constexpr int NT = NCO / 16;       // n-tiles per wave
    constexpr int IN3 = IND * IND * IND;
    constexpr int OD3 = OUTD * OUTD * OUTD;

    __shared__ __align__(16) unsigned char smem[S * 64];

    int n = blockIdx.y;
    int bt = blockIdx.x;
    int z = bt / (OUTD / 2);
    int y0 = (bt % (OUTD / 2)) * 2;

    int tid = threadIdx.x;
    int lane = tid & 63;
    int g = lane >> 4;

    // per-lane A read addresses for the 27 taps (chunk-invariant)
    int am = (tid >> 6) * 16 + (lane & 15);
    if (am > MT - 1) am = MT - 1;
    int ry = (am >= OUTD) ? 1 : 0;
    int ax = am - ry * OUTD;
    int addrA[27];
    #pragma unroll
    for (int kz = 0; kz < 3; ++kz)
        #pragma unroll
        for (int ky = 0; ky < 3; ++ky)
            #pragma unroll
            for (int kx = 0; kx < 3; ++kx) {
                int p = (kz * 4 + ry + ky) * XE + (ax + kx);
                addrA[(kz * 3 + ky) * 3 + kx] = p * 64 + (((g ^ (p >> 1)) & 3) << 4);
            }

    f32x4 acc[NT];
    #pragma unroll
    for (int nt = 0; nt < NT; ++nt)
        #pragma unroll
        for (int rr = 0; rr < 4; ++rr) acc[nt][rr] = 0.f;

    const int nth = W * 64;

    for (int c = 0; c < CHUNKS; ++c) {
        if (c) __syncthreads();
        // ---- stage: global fp32 (x-coalesced) -> LDS bf16 ci-contiguous ----
        const float* gin = in + ((size_t)(n * in_ctot) + in_coff + c * 32) * IN3;
        for (int idx = tid; idx < S; idx += nth) {
            int dz = idx / (4 * XE);
            int rem = idx % (4 * XE);
            int dy = rem / XE;
            int ix = rem % XE;
            int zz, yy, xx;
            if (PAD) {
                zz = z + dz - 2;  zz = zz < 0 ? 0 : (zz > IND - 1 ? IND - 1 : zz);
                yy = y0 + dy - 2; yy = yy < 0 ? 0 : (yy > IND - 1 ? IND - 1 : yy);
                xx = ix - 2;      xx = xx < 0 ? 0 : (xx > IND - 1 ? IND - 1 : xx);
            } else {
                zz = z + dz; yy = y0 + dy; xx = ix;
            }
            const float* gp = gin + ((size_t)zz * IND + yy) * IND + xx;
            #pragma unroll
            for (int e8 = 0; e8 < 4; ++e8) {
                u32x4 u;
                #pragma unroll
                for (int jp = 0; jp < 4; ++jp) {
                    int cil = e8 * 8 + jp * 2;
                    float f0 = (c * 32 + cil < CIN) ? gp[(size_t)cil * IN3] : 0.f;
                    float f1 = (c * 32 + cil + 1 < CIN) ? gp[(size_t)(cil + 1) * IN3] : 0.f;
                    u[jp] = (unsigned int)f2bf(f0) | ((unsigned int)f2bf(f1) << 16);
                }
                *(u32x4*)(smem + idx * 64 + (((e8 ^ (idx >> 1)) & 3) << 4)) = u;
            }
        }
        __syncthreads();
        // ---- compute: 27 taps x NT mfma ----
        const unsigned short* bbase = Bt + ((size_t)(c * 27) * NCO) * 32 +
                                      (size_t)(lane & 15) * 32 + g * 8;
        #pragma unroll
        for (int t = 0; t < 27; ++t) {
            short8 af = *(const short8*)(smem + addrA[t]);
            #pragma unroll
            for (int nt = 0; nt < NT; ++nt) {
                short8 bf = *(const short8*)(bbase + ((size_t)t * NCO + nt * 16) * 32);
                acc[nt] = __builtin_amdgcn_mfma_f32_16x16x32_bf16(af, bf, acc[nt], 0, 0, 0);
            }
        }
    }

    // ---- store (C/D layout) ----
    int co0 = lane & 15;
    #pragma unroll
    for (int nt = 0; nt < NT; ++nt) {
        int co = out_coff + nt * 16 + co0;
        #pragma unroll
        for (int rr = 0; rr < 4; ++rr) {
            int m = (tid >> 6) * 16 + g * 4 + rr;
            if (m < MT) {
                int ryo = (m >= OUTD) ? 1 : 0;
                int xo = m - ryo * OUTD;
                float v = acc[nt][rr] * BNS;
                if (RELU) v = v > 0.f ? v : 0.f;
                out[((size_t)(n * out_ctot) + co) * OD3 +
                    ((size_t)z * OUTD + (y0 + ryo)) * OUTD + xo] = v;
            }
        }
    }
}

// ---------------- generic small fp32 conv (kept for pb) ----------------
template <int CIN, int COUT, int IND, int OUTD, bool PAD, bool RELU>
__global__ __launch_bounds__(256) void k_conv3(const float* __restrict__ in,
                                               const float* __restrict__ wT,
                                               float* __restrict__ out,
                                               int in_ctot, int in_coff,
                                               int out_ctot, int out_coff) {
    constexpr int IN3 = IND * IND * IND;
    constexpr int OD3 = OUTD * OUTD * OUTD;
    int n = blockIdx.y;
    int s = blockIdx.x * 256 + threadIdx.x;
    if (s >= OD3) return;
    int z = s / (OUTD * OUTD);
    int r = s % (OUTD * OUTD);
    int y = r / OUTD;
    int x = r % OUTD;

    int offs[27];
    #pragma unroll
    for (int kz = 0; kz < 3; ++kz) {
        int zz = PAD ? z + kz - 2 : z + kz;
        if (PAD) zz = zz < 0 ? 0 : (zz > IND - 1 ? IND - 1 : zz);
        #pragma unroll
        for (int ky = 0; ky < 3; ++ky) {
            int yy = PAD ? y + ky - 2 : y + ky;
            if (PAD) yy = yy < 0 ? 0 : (yy > IND - 1 ? IND - 1 : yy);
            #pragma unroll
            for (int kx = 0; kx < 3; ++kx) {
                int xx = PAD ? x + kx - 2 : x + kx;
                if (PAD) xx = xx < 0 ? 0 : (xx > IND - 1 ? IND - 1 : xx);
                offs[(kz * 3 + ky) * 3 + kx] = (zz * IND + yy) * IND + xx;
            }
        }
    }

    float acc[COUT];
    #pragma unroll
    for (int c = 0; c < COUT; ++c) acc[c] = 0.f;

    const float* inN = in + ((size_t)n * in_ctot + in_coff) * IN3;
    for (int ci = 0; ci < CIN; ++ci) {
        const float* pc = inN + (size_t)ci * IN3;
        const float* wci = wT + ci * 27 * COUT;
        #pragma unroll
        for (int t = 0; t < 27; ++t) {
            float v = pc[offs[t]];
            const float* wp = wci + t * COUT;
            #pragma unroll
            for (int co = 0; co < COUT; ++co) acc[co] = fmaf(v, wp[co], acc[co]);
        }
    }

    float* o = out + ((size_t)n * out_ctot + out_coff) * OD3 + s;
    #pragma unroll
    for (int co = 0; co < COUT; ++co) {
        float v = acc[co] * BNS;
        if (RELU) v = v > 0.f ? v : 0.f;
        o[(size_t)co * OD3] = v;
    }
}

// ---------------- maxpool 3x3x3 stride 3 ----------------
__global__ __launch_bounds__(256) void k_pool3(const float* __restrict__ in,
                                               float* __restrict__ out,
                                               int nbase, int ncnt) {
    int i = blockIdx.x * 256 + threadIdx.x;
    if (i >= ncnt * 16 * 1000) return;
    int x = i % 10;
    int y = (i / 10) % 10;
    int z = (i / 100) % 10;
    int nc = i / 1000;
    const float* p = in + (size_t)nc * 27000;
    float m = -INFINITY;
    #pragma unroll
    for (int dz = 0; dz < 3; ++dz)
        #pragma unroll
        for (int dy = 0; dy < 3; ++dy)
            #pragma unroll
            for (int dx = 0; dx < 3; ++dx)
                m = fmaxf(m, p[((3 * z + dz) * 30 + 3 * y + dy) * 30 + 3 * x + dx]);
    out[((size_t)nbase * 16 + nc) * 1000 + (z * 100 + y * 10 + x)] = m;
}

// ---------------- maxpool4 + linear + softmax + threshold ----------------
__global__ __launch_bounds__(64) void k_final(const float* __restrict__ p2,
                                              const float* __restrict__ wlin,
                                              const float* __restrict__ blin,
                                              float* __restrict__ dout) {
    int n = blockIdx.x;
    int t = threadIdx.x;
    int c = t >> 3, dz = (t >> 2) & 1, dy = (t >> 1) & 1, dx = t & 1;
    const float* p = p2 + ((size_t)n * 8 + c) * 512;
    float m = -INFINITY;
    #pragma unroll
    for (int iz = 0; iz < 4; ++iz)
        #pragma unroll
        for (int iy = 0; iy < 4; ++iy)
            #pragma unroll
            for (int ix = 0; ix < 4; ++ix)
                m = fmaxf(m, p[((dz * 4 + iz) * 8 + dy * 4 + iy) * 8 + dx * 4 + ix]);
    __shared__ float h[64];
    __shared__ float lg[3];
    h[t] = m;
    __syncthreads();
    if (t < 3) {
        float acc = blin[t];
        for (int k = 0; k < 64; ++k) acc += h[k] * wlin[t * 64 + k];
        lg[t] = acc;
    }
    __syncthreads();
    if (t == 0) {
        float mx = fmaxf(fmaxf(lg[0], lg[1]), lg[2]);
        float e0 = expf(lg[0] - mx), e1 = expf(lg[1] - mx), e2 = expf(lg[2] - mx);
        float inv = 1.f / (e0 + e1 + e2);
        dout[n * 3 + 0] = e0 * inv;
        dout[n * 3 + 1] = e1 * inv;
        dout[n * 3 + 2] = e2 * inv;
        dout[81 + n] = (e2 * inv) > 0.1f ? 1.0f : 0.0f;
    }
}

extern "C" void kernel_launch(void* const* d_in, const int* in_sizes, int n_in,
                              void* d_out, int out_size, void* d_ws, size_t ws_size,
                              hipStream_t stream) {
    const float* tsdf  = (const float*)d_in[0];
    const float* prev  = (const float*)d_in[1];
    const float* w_upt = (const float*)d_in[2];
    const float* w_upc = (const float*)d_in[3];
    const float* w_ts1 = (const float*)d_in[4];
    const float* w_ts2 = (const float*)d_in[5];
    const float* w_b1a = (const float*)d_in[6];
    const float* w_b1b = (const float*)d_in[7];
    const float* w_pa  = (const float*)d_in[8];
    const float* w_pb  = (const float*)d_in[9];
    const float* w_lin = (const float*)d_in[10];
    const float* b_lin = (const float*)d_in[11];
    float* dout = (float*)d_out;

    float* ws = (float*)d_ws;
    size_t off = 0;
    auto alloc = [&](size_t nel) {
        float* p = ws + off;
        off += (nel + 63) & ~(size_t)63;
        return p;
    };
    auto alloc_us = [&](size_t nel) {  // ushort alloc
        return (unsigned short*)alloc((nel + 1) / 2);
    };

    // fixed small buffers
    float* P1     = alloc((size_t)27 * 16 * 1000);
    float* P2     = alloc((size_t)27 * 8 * 512);
    float* wT_upt = alloc(32 * 64 * 32);
    float* wT_ts1 = alloc(1 * 27 * 16);
    float* wT_pb  = alloc(16 * 27 * 8);
    unsigned short* Bt_upc = alloc_us((size_t)1 * 27 * 32 * 32);
    unsigned short* Bt_ts2 = alloc_us((size_t)1 * 27 * 16 * 32);
    unsigned short* Bt_b1a = alloc_us((size_t)2 * 27 * 32 * 32);
    unsigned short* Bt_b1b = alloc_us((size_t)1 * 27 * 32 * 32);
    unsigned short* Bt_pa  = alloc_us((size_t)1 * 27 * 16 * 32);
    size_t fixed_floats = off;

    // chunked A (34^3 x 32ch) and C (32^3 x 48ch) buffers
    const size_t perA = (size_t)32 * 39304 + 64;
    const size_t perC = (size_t)48 * 32768 + 64;
    const size_t per_block = perA + perC;
    size_t avail = ws_size / 4 > fixed_floats ? ws_size / 4 - fixed_floats : 0;
    int NB = (int)(avail / per_block);
    if (NB > 27) NB = 27;
    if (NB < 1) NB = 1;

    float* bufA = alloc((size_t)NB * 32 * 39304);
    float* bufC = alloc((size_t)NB * 48 * 32768);

    // weight prep
    k_tr_convT<<<cdiv(32 * 64 * 32, 256), 256, 0, stream>>>(w_upt, wT_upt);
    k_tr_conv<<<cdiv(1 * 16 * 27, 256), 256, 0, stream>>>(w_ts1, wT_ts1, 1, 16);
    k_tr_conv<<<cdiv(16 * 8 * 27, 256), 256, 0, stream>>>(w_pb, wT_pb, 16, 8);
    k_trw<<<cdiv(1 * 27 * 32 * 32, 256), 256, 0, stream>>>(w_upc, Bt_upc, 32, 1, 32);
    k_trw<<<cdiv(1 * 27 * 16 * 32, 256), 256, 0, stream>>>(w_ts2, Bt_ts2, 16, 1, 16);
    k_trw<<<cdiv(2 * 27 * 32 * 32, 256), 256, 0, stream>>>(w_b1a, Bt_b1a, 48, 2, 32);
    k_trw<<<cdiv(1 * 27 * 32 * 32, 256), 256, 0, stream>>>(w_b1b, Bt_b1b, 32, 1, 32);
    k_trw<<<cdiv(1 * 27 * 16 * 32, 256), 256, 0, stream>>>(w_pa, Bt_pa, 32, 1, 16);

    for (int n0 = 0; n0 < 27; n0 += NB) {
        int nc = 27 - n0 < NB ? 27 - n0 : NB;

        // prevs path: convT -> upc (MFMA) into bufC ch0..31
        k_convT<<<dim3(cdiv(17 * 17 * 17, 256), 8, nc), 256, 0, stream>>>(prev, wT_upt, bufA, n0);
        k_cmfma<32, 1, 34, 32, false, false, 32>
            <<<dim3(32 * 16, nc), 256, 0, stream>>>(bufA, Bt_upc, bufC, 32, 0, 48, 0);

        // tsdf path: ts1 -> ts2 (MFMA) into bufC ch32..47
        k_ts1<<<dim3(cdiv(39304, 256), nc), 256, 0, stream>>>(tsdf, wT_ts1, bufA, n0);
        k_cmfma<16, 1, 34, 32, false, false, 16>
            <<<dim3(32 * 16, nc), 256, 0, stream>>>(bufA, Bt_ts2, bufC, 16, 0, 48, 32);

        // fuse block: b1a (pad+relu, MFMA) -> b1b (MFMA) = feat into bufC ch0..31
        k_cmfma<48, 2, 32, 34, true, true, 32>
            <<<dim3(34 * 17, nc), 320, 0, stream>>>(bufC, Bt_b1a, bufA, 48, 0, 32, 0);
        k_cmfma<32, 1, 34, 32, false, false, 32>
            <<<dim3(32 * 16, nc), 256, 0, stream>>>(bufA, Bt_b1b, bufC, 32, 0, 32, 0);

        // pred conv a (MFMA) + pool3
        k_cmfma<32, 1, 32, 30, false, true, 16>
            <<<dim3(30 * 15, nc), 256, 0, stream>>>(bufC, Bt_pa, bufA, 32, 0, 16, 0);
        k_pool3<<<cdiv(nc * 16 * 1000, 256), 256, 0, stream>>>(bufA, P1, n0, nc);
    }

    // tail
    k_conv3<16, 8, 10, 8, false, true>
        <<<dim3(cdiv(512, 256), 27), 256, 0, stream>>>(P1, wT_pb, P2, 16, 0, 8, 0);
    k_final<<<27, 64, 0, stream>>>(P2, w_lin, b_lin, dout);
}

// Round 5
// 871.442 us; speedup vs baseline: 5.8306x; 2.0130x over previous
//
#include <hip/hip_runtime.h>
#include <math.h>

// 1/sqrt(1+1e-5) — eval BatchNorm with default stats
#define BNS 0.9999950000374997f

static inline int cdiv(int a, int b) { return (a + b - 1) / b; }

typedef short short8 __attribute__((ext_vector_type(8)));
typedef float f32x4 __attribute__((ext_vector_type(4)));
typedef unsigned int u32x4 __attribute__((ext_vector_type(4)));

__device__ __forceinline__ unsigned short f2bf(float f) {
    unsigned int u = __float_as_uint(f);
    u += 0x7fffu + ((u >> 16) & 1u);
    return (unsigned short)(u >> 16);
}
__device__ __forceinline__ float bf2f(unsigned short u) {
    return __uint_as_float(((unsigned int)u) << 16);
}

// per-n element strides of the big NDHWC ushort buffers
#define U1 ((size_t)39304 * 48)   // 34^3 x 48ch
#define U2 ((size_t)32768 * 48)   // 32^3 x 48ch
#define U3 ((size_t)39304 * 32)   // 34^3 x 32ch

// ---------------- weight prep ----------------
// fp32 path: w[co][ci][27] (OIDHW) -> wT[ci][tap][co]
__global__ void k_tr_conv(const float* __restrict__ w, float* __restrict__ wT,
                          int CIN, int COUT) {
    int i = blockIdx.x * 256 + threadIdx.x;
    int total = CIN * COUT * 27;
    if (i >= total) return;
    int co = i % COUT;
    int tap = (i / COUT) % 27;
    int ci = i / (COUT * 27);
    wT[i] = w[(co * CIN + ci) * 27 + tap];
}

// MFMA conv weights: w[co][ci][27] fp32 -> Bt bf16 [chunk][tap][co][ci_local(32)], zero-pad ci
__global__ void k_trw(const float* __restrict__ w, unsigned short* __restrict__ Bt,
                      int CIN, int CHUNKS, int NCO) {
    int i = blockIdx.x * 256 + threadIdx.x;
    int total = CHUNKS * 27 * NCO * 32;
    if (i >= total) return;
    int cil = i & 31;
    int n = (i >> 5) % NCO;
    int t = (i / (32 * NCO)) % 27;
    int c = i / (32 * NCO * 27);
    int ci = c * 32 + cil;
    float v = (ci < CIN) ? w[(n * CIN + ci) * 27 + t] : 0.f;
    Bt[i] = f2bf(v);
}

// convT weights: w[ci=32][co=32][64tap] (IODHW) -> BtT bf16 [tap][co][ci]
__global__ void k_trwT(const float* __restrict__ w, unsigned short* __restrict__ Bt) {
    int i = blockIdx.x * 256 + threadIdx.x;
    if (i >= 64 * 32 * 32) return;
    int cil = i & 31;
    int co = (i >> 5) & 31;
    int tap = i >> 10;
    Bt[i] = f2bf(w[(cil * 32 + co) * 64 + tap]);
}

// prev [27][32][4096] fp32 NCDHW -> prevT [27][4096][32] bf16 NDHWC (LDS transpose)
__global__ __launch_bounds__(256) void k_tprev(const float* __restrict__ prev,
                                               unsigned short* __restrict__ out) {
    __shared__ float t32[32][65];
    int n = blockIdx.y;
    int p0 = blockIdx.x * 64;
    int tid = threadIdx.x;
    #pragma unroll
    for (int it = 0; it < 8; ++it) {
        int idx = it * 256 + tid;
        int ci = idx >> 6;
        int dp = idx & 63;
        t32[ci][dp] = prev[((size_t)n * 32 + ci) * 4096 + p0 + dp];
    }
    __syncthreads();
    int dp = tid >> 2;
    int cq = (tid & 3) * 8;
    u32x4 u;
    #pragma unroll
    for (int j = 0; j < 4; ++j) {
        u[j] = (unsigned int)f2bf(t32[cq + 2 * j][dp]) |
               ((unsigned int)f2bf(t32[cq + 2 * j + 1][dp]) << 16);
    }
    *(u32x4*)(out + ((size_t)n * 4096 + p0 + dp) * 32 + cq) = u;
}

// ---------------- ts1: carve tsdf block, replicate-pad-2, conv 1->16, relu(x*BNS), bf16 NDHWC out
__global__ __launch_bounds__(256) void k_ts1(const float* __restrict__ tsdf,
                                             const float* __restrict__ wT,
                                             unsigned short* __restrict__ buf1, int nbase) {
    int n = blockIdx.y;
    int ng = nbase + n;
    int a1 = ng / 9, b1 = (ng / 3) % 3, c1 = ng % 3;
    int s = blockIdx.x * 256 + threadIdx.x;
    if (s >= 39304) return;
    int z = s / (34 * 34);
    int r = s % (34 * 34);
    int y = r / 34;
    int x = r % 34;

    int base = (a1 * 32 * 96 + b1 * 32) * 96 + c1 * 32;
    int offs[27];
    #pragma unroll
    for (int kz = 0; kz < 3; ++kz) {
        int zz = z + kz - 2; zz = zz < 0 ? 0 : (zz > 31 ? 31 : zz);
        #pragma unroll
        for (int ky = 0; ky < 3; ++ky) {
            int yy = y + ky - 2; yy = yy < 0 ? 0 : (yy > 31 ? 31 : yy);
            #pragma unroll
            for (int kx = 0; kx < 3; ++kx) {
                int xx = x + kx - 2; xx = xx < 0 ? 0 : (xx > 31 ? 31 : xx);
                offs[(kz * 3 + ky) * 3 + kx] = zz * 9216 + yy * 96 + xx;
            }
        }
    }

    float acc[16];
    #pragma unroll
    for (int c = 0; c < 16; ++c) acc[c] = 0.f;

    const float* p = tsdf + base;
    #pragma unroll
    for (int t = 0; t < 27; ++t) {
        float v = p[offs[t]];
        const float* wp = wT + t * 16;
        #pragma unroll
        for (int co = 0; co < 16; ++co) acc[co] = fmaf(v, wp[co], acc[co]);
    }

    unsigned short* o = buf1 + (size_t)n * U1 + (size_t)s * 48 + 32;
    #pragma unroll
    for (int co = 0; co < 16; ++co) {
        float v = acc[co] * BNS;
        o[co] = f2bf(v > 0.f ? v : 0.f);
    }
}

// ---------------- MFMA implicit-GEMM 3^3 conv, NDHWC bf16 -> NDHWC bf16 ----------------
// WG tile: 1 z x 4 y x OUTD x.  Wave owns 32 positions (two 16-m subtiles, B reused).
// LDS: [pos][80B] (4 data slots of 16B + 16B pad -> conflict-free ds_read_b128).
// A frag: lane = (m = lane&15 within subtile, k-slice g=lane>>4); B from global (L1-hot).
// C/D: col(co)=lane&15, row(m16)=g*4+rr  [HW-verified, validated in R4].
template <int KR, int CSTRIDE, int CINOFF, int CH, int NCO, int COSTRIDE, int COOFF,
          int IND, int OUTD, bool PAD, bool RELU, int NW>
__global__ __launch_bounds__(NW * 64) void
k_cm(const unsigned short* __restrict__ in, const unsigned short* __restrict__ Bt,
     unsigned short* __restrict__ out, size_t inNS, size_t outNS) {
    constexpr int XE = OUTD + 2;
    constexpr int YS = 6;
    constexpr int S = 3 * YS * XE;
    constexpr int MT = 4 * OUTD;
    constexpr int YT = (OUTD + 3) / 4;
    constexpr int NT = NCO / 16;

    __shared__ __align__(16) unsigned char smem[S * 80];

    int n = blockIdx.y;
    int bt = blockIdx.x;
    int yt = bt % YT, z = bt / YT;
    int y0 = yt * 4;

    int tid = threadIdx.x;
    int lane = tid & 63;
    int g = lane >> 4;
    int wv = tid >> 6;

    int mb = wv * 32 + (lane & 15);
    int m0 = mb < MT ? mb : MT - 1;
    int m1 = (mb + 16) < MT ? (mb + 16) : MT - 1;
    int dy0 = m0 / OUTD, x0 = m0 - dy0 * OUTD;
    int dy1 = m1 / OUTD, x1 = m1 - dy1 * OUTD;
    int pb0 = (dy0 * XE + x0) * 80 + g * 16;
    int pb1 = (dy1 * XE + x1) * 80 + g * 16;

    const unsigned short* inN = in + (size_t)n * inNS;
    unsigned short* outN = out + (size_t)n * outNS;

    f32x4 acc[2][NT];
    #pragma unroll
    for (int s2 = 0; s2 < 2; ++s2)
        #pragma unroll
        for (int nt = 0; nt < NT; ++nt)
            #pragma unroll
            for (int rr = 0; rr < 4; ++rr) acc[s2][nt][rr] = 0.f;

    for (int c = 0; c < CH; ++c) {
        if (c) __syncthreads();
        for (int i = tid; i < S * 4; i += NW * 64) {
            int pos = i >> 2, slot = i & 3;
            int dz = pos / (YS * XE);
            int rem = pos - dz * (YS * XE);
            int dyy = rem / XE;
            int ix = rem - dyy * XE;
            int zz, yy, xx;
            if (PAD) {
                zz = z + dz - 2;  zz = zz < 0 ? 0 : (zz > IND - 1 ? IND - 1 : zz);
                yy = y0 + dyy - 2; yy = yy < 0 ? 0 : (yy > IND - 1 ? IND - 1 : yy);
                xx = ix - 2;      xx = xx < 0 ? 0 : (xx > IND - 1 ? IND - 1 : xx);
            } else {
                zz = z + dz;
                yy = y0 + dyy; yy = yy > IND - 1 ? IND - 1 : yy;
                xx = ix;
            }
            u32x4 v = {0u, 0u, 0u, 0u};
            if (c * 32 + slot * 8 < KR) {
                v = *(const u32x4*)(inN + ((size_t)(zz * IND + yy) * IND + xx) * CSTRIDE +
                                    CINOFF + c * 32 + slot * 8);
            }
            *(u32x4*)(smem + pos * 80 + slot * 16) = v;
        }
        __syncthreads();

        const unsigned short* bb =
            Bt + ((size_t)(c * 27) * NCO + (lane & 15)) * 32 + g * 8;
        #pragma unroll
        for (int t = 0; t < 27; ++t) {
            int toff = (((t / 9) * YS + (t / 3) % 3) * XE + t % 3) * 80;
            short8 a0 = *(const short8*)(smem + pb0 + toff);
            short8 a1 = *(const short8*)(smem + pb1 + toff);
            #pragma unroll
            for (int nt = 0; nt < NT; ++nt) {
                short8 bf = *(const short8*)(bb + ((size_t)t * NCO + nt * 16) * 32);
                acc[0][nt] = __builtin_amdgcn_mfma_f32_16x16x32_bf16(a0, bf, acc[0][nt], 0, 0, 0);
                acc[1][nt] = __builtin_amdgcn_mfma_f32_16x16x32_bf16(a1, bf, acc[1][nt], 0, 0, 0);
            }
        }
    }

    int co0 = lane & 15;
    #pragma unroll
    for (int sub = 0; sub < 2; ++sub) {
        #pragma unroll
        for (int rr = 0; rr < 4; ++rr) {
            int m = wv * 32 + sub * 16 + g * 4 + rr;
            if (m < MT) {
                int dy = m / OUTD, xo = m - dy * OUTD;
                if (y0 + dy < OUTD) {
                    size_t ob = ((size_t)(z * OUTD + y0 + dy) * OUTD + xo) * COSTRIDE + COOFF;
                    #pragma unroll
                    for (int nt = 0; nt < NT; ++nt) {
                        float v = acc[sub][nt][rr] * BNS;
                        if (RELU) v = v > 0.f ? v : 0.f;
                        outN[ob + nt * 16 + co0] = f2bf(v);
                    }
                }
            }
        }
    }
}

// ---------------- convT as MFMA: prevT[ng][4096][32] bf16 -> buf1 c0..31, relu(x*BNS) ------
// parity class q = blockIdx.y; output (2tz+pz, 2ty+py, 2tx+px); 8 taps, zero-masked halo.
__global__ __launch_bounds__(192) void
k_cT(const unsigned short* __restrict__ prevT, const unsigned short* __restrict__ Bt,
     unsigned short* __restrict__ buf1, int nbase) {
    constexpr int XE = 19, YS = 5, S = 2 * YS * XE;  // 190 positions
    constexpr int MT = 68;

    __shared__ __align__(16) unsigned char smem[S * 80];

    int n = blockIdx.z;
    int ng = nbase + n;
    int q = blockIdx.y;
    int px = q & 1, py = (q >> 1) & 1, pz = q >> 2;
    int bt = blockIdx.x;
    int yt = bt % 5, z = bt / 5;
    int ty0 = yt * 4;

    int tid = threadIdx.x;
    int lane = tid & 63;
    int g = lane >> 4;
    int wv = tid >> 6;

    int mb = wv * 32 + (lane & 15);
    int m0 = mb < MT ? mb : MT - 1;
    int m1 = (mb + 16) < MT ? (mb + 16) : MT - 1;
    int dy0 = m0 / 17, x0 = m0 - dy0 * 17;
    int dy1 = m1 / 17, x1 = m1 - dy1 * 17;
    int pb0 = (dy0 * XE + x0) * 80 + g * 16;
    int pb1 = (dy1 * XE + x1) * 80 + g * 16;

    const unsigned short* inN = prevT + (size_t)ng * 4096 * 32;

    // stage (zero-masked OOB)
    for (int i = tid; i < S * 4; i += 192) {
        int pos = i >> 2, slot = i & 3;
        int dz = pos / (YS * XE);
        int rem = pos - dz * (YS * XE);
        int dyy = rem / XE;
        int ix = rem - dyy * XE;
        int iz = z - 1 + dz;
        int iy = ty0 - 1 + dyy;
        int ixx = ix - 1;
        u32x4 v = {0u, 0u, 0u, 0u};
        if ((unsigned)iz < 16u && (unsigned)iy < 16u && (unsigned)ixx < 16u) {
            v = *(const u32x4*)(inN + ((size_t)(iz * 16 + iy) * 16 + ixx) * 32 + slot * 8);
        }
        *(u32x4*)(smem + pos * 80 + slot * 16) = v;
    }
    __syncthreads();

    int kz0 = 1 - pz, ky0 = 1 - py, kx0 = 1 - px;

    f32x4 acc[2][2];
    #pragma unroll
    for (int s2 = 0; s2 < 2; ++s2)
        #pragma unroll
        for (int nt = 0; nt < 2; ++nt)
            #pragma unroll
            for (int rr = 0; rr < 4; ++rr) acc[s2][nt][rr] = 0.f;

    #pragma unroll
    for (int cz = 0; cz < 2; ++cz)
        #pragma unroll
        for (int cy = 0; cy < 2; ++cy)
            #pragma unroll
            for (int cx = 0; cx < 2; ++cx) {
                int toff = ((cz * YS + cy) * XE + cx) * 80;
                int tapg = (((kz0 + 2 * cz) * 4 + (ky0 + 2 * cy)) * 4 + (kx0 + 2 * cx));
                const unsigned short* bb =
                    Bt + ((size_t)tapg * 32 + (lane & 15)) * 32 + g * 8;
                short8 a0 = *(const short8*)(smem + pb0 + toff);
                short8 a1 = *(const short8*)(smem + pb1 + toff);
                #pragma unroll
                for (int nt = 0; nt < 2; ++nt) {
                    short8 bf = *(const short8*)(bb + (size_t)nt * 16 * 32);
                    acc[0][nt] = __builtin_amdgcn_mfma_f32_16x16x32_bf16(a0, bf, acc[0][nt], 0, 0, 0);
                    acc[1][nt] = __builtin_amdgcn_mfma_f32_16x16x32_bf16(a1, bf, acc[1][nt], 0, 0, 0);
                }
            }

    unsigned short* outN = buf1 + (size_t)n * U1;
    int co0 = lane & 15;
    #pragma unroll
    for (int sub = 0; sub < 2; ++sub) {
        #pragma unroll
        for (int rr = 0; rr < 4; ++rr) {
            int m = wv * 32 + sub * 16 + g * 4 + rr;
            if (m < MT) {
                int dy = m / 17, tx = m - dy * 17;
                if (ty0 + dy < 17) {
                    int oz = 2 * z + pz, oy = 2 * (ty0 + dy) + py, ox = 2 * tx + px;
                    size_t ob = ((size_t)(oz * 34 + oy) * 34 + ox) * 48;
                    #pragma unroll
                    for (int nt = 0; nt < 2; ++nt) {
                        float v = acc[sub][nt][rr] * BNS;
                        outN[ob + nt * 16 + co0] = f2bf(v > 0.f ? v : 0.f);
                    }
                }
            }
        }
    }
}

// ---------------- maxpool3 (NDHWC bf16 in) -> P1 fp32 NCDHW ----------------
__global__ __launch_bounds__(256) void k_pool3(const unsigned short* __restrict__ pa,
                                               float* __restrict__ out,
                                               int nbase, int ncnt) {
    int i = blockIdx.x * 256 + threadIdx.x;
    if (i >= ncnt * 16000) return;
    int c = i & 15;
    int rest = i >> 4;
    int x = rest % 10;
    int y = (rest / 10) % 10;
    int z = (rest / 100) % 10;
    int nl = rest / 1000;
    const unsigned short* p = pa + (size_t)nl * U2;
    float m = -INFINITY;
    #pragma unroll
    for (int dz = 0; dz < 3; ++dz)
        #pragma unroll
        for (int dy = 0; dy < 3; ++dy)
            #pragma unroll
            for (int dx = 0; dx < 3; ++dx)
                m = fmaxf(m, bf2f(p[((size_t)((3 * z + dz) * 30 + 3 * y + dy) * 30 +
                                    (3 * x + dx)) * 16 + c]));
    out[((size_t)(nbase + nl) * 16 + c) * 1000 + (z * 100 + y * 10 + x)] = m;
}

// ---------------- small fp32 conv for pb ----------------
template <int CIN, int COUT, int IND, int OUTD>
__global__ __launch_bounds__(256) void k_conv3(const float* __restrict__ in,
                                               const float* __restrict__ wT,
                                               float* __restrict__ out) {
    constexpr int IN3 = IND * IND * IND;
    constexpr int OD3 = OUTD * OUTD * OUTD;
    int n = blockIdx.y;
    int s = blockIdx.x * 256 + threadIdx.x;
    if (s >= OD3) return;
    int z = s / (OUTD * OUTD);
    int r = s % (OUTD * OUTD);
    int y = r / OUTD;
    int x = r % OUTD;

    int offs[27];
    #pragma unroll
    for (int kz = 0; kz < 3; ++kz)
        #pragma unroll
        for (int ky = 0; ky < 3; ++ky)
            #pragma unroll
            for (int kx = 0; kx < 3; ++kx)
                offs[(kz * 3 + ky) * 3 + kx] = ((z + kz) * IND + y + ky) * IND + x + kx;

    float acc[COUT];
    #pragma unroll
    for (int c = 0; c < COUT; ++c) acc[c] = 0.f;

    const float* inN = in + (size_t)n * CIN * IN3;
    for (int ci = 0; ci < CIN; ++ci) {
        const float* pc = inN + (size_t)ci * IN3;
        const float* wci = wT + ci * 27 * COUT;
        #pragma unroll
        for (int t = 0; t < 27; ++t) {
            float v = pc[offs[t]];
            const float* wp = wci + t * COUT;
            #pragma unroll
            for (int co = 0; co < COUT; ++co) acc[co] = fmaf(v, wp[co], acc[co]);
        }
    }

    float* o = out + (size_t)n * COUT * OD3 + s;
    #pragma unroll
    for (int co = 0; co < COUT; ++co) {
        float v = acc[co] * BNS;
        o[(size_t)co * OD3] = v > 0.f ? v : 0.f;
    }
}

// ---------------- maxpool4 + linear + softmax + threshold ----------------
__global__ __launch_bounds__(64) void k_final(const float* __restrict__ p2,
                                              const float* __restrict__ wlin,
                                              const float* __restrict__ blin,
                                              float* __restrict__ dout) {
    int n = blockIdx.x;
    int t = threadIdx.x;
    int c = t >> 3, dz = (t >> 2) & 1, dy = (t >> 1) & 1, dx = t & 1;
    const float* p = p2 + ((size_t)n * 8 + c) * 512;
    float m = -INFINITY;
    #pragma unroll
    for (int iz = 0; iz < 4; ++iz)
        #pragma unroll
        for (int iy = 0; iy < 4; ++iy)
            #pragma unroll
            for (int ix = 0; ix < 4; ++ix)
                m = fmaxf(m, p[((dz * 4 + iz) * 8 + dy * 4 + iy) * 8 + dx * 4 + ix]);
    __shared__ float h[64];
    __shared__ float lg[3];
    h[t] = m;
    __syncthreads();
    if (t < 3) {
        float acc = blin[t];
        for (int k = 0; k < 64; ++k) acc += h[k] * wlin[t * 64 + k];
        lg[t] = acc;
    }
    __syncthreads();
    if (t == 0) {
        float mx = fmaxf(fmaxf(lg[0], lg[1]), lg[2]);
        float e0 = expf(lg[0] - mx), e1 = expf(lg[1] - mx), e2 = expf(lg[2] - mx);
        float inv = 1.f / (e0 + e1 + e2);
        dout[n * 3 + 0] = e0 * inv;
        dout[n * 3 + 1] = e1 * inv;
        dout[n * 3 + 2] = e2 * inv;
        dout[81 + n] = (e2 * inv) > 0.1f ? 1.0f : 0.0f;
    }
}

extern "C" void kernel_launch(void* const* d_in, const int* in_sizes, int n_in,
                              void* d_out, int out_size, void* d_ws, size_t ws_size,
                              hipStream_t stream) {
    const float* tsdf  = (const float*)d_in[0];
    const float* prev  = (const float*)d_in[1];
    const float* w_upt = (const float*)d_in[2];
    const float* w_upc = (const float*)d_in[3];
    const float* w_ts1 = (const float*)d_in[4];
    const float* w_ts2 = (const float*)d_in[5];
    const float* w_b1a = (const float*)d_in[6];
    const float* w_b1b = (const float*)d_in[7];
    const float* w_pa  = (const float*)d_in[8];
    const float* w_pb  = (const float*)d_in[9];
    const float* w_lin = (const float*)d_in[10];
    const float* b_lin = (const float*)d_in[11];
    float* dout = (float*)d_out;

    char* base = (char*)d_ws;
    size_t off = 0;
    auto alB = [&](size_t bytes) {
        off = (off + 255) & ~(size_t)255;
        void* p = base + off;
        off += bytes;
        return p;
    };

    float* P1      = (float*)alB((size_t)27 * 16 * 1000 * 4);
    float* P2      = (float*)alB((size_t)27 * 8 * 512 * 4);
    float* wT_ts1  = (float*)alB(27 * 16 * 4);
    float* wT_pb   = (float*)alB((size_t)16 * 27 * 8 * 4);
    unsigned short* prevT   = (unsigned short*)alB((size_t)27 * 4096 * 32 * 2);
    unsigned short* BtT_upt = (unsigned short*)alB((size_t)64 * 32 * 32 * 2);
    unsigned short* Bt_upc  = (unsigned short*)alB((size_t)27 * 32 * 32 * 2);
    unsigned short* Bt_ts2  = (unsigned short*)alB((size_t)27 * 16 * 32 * 2);
    unsigned short* Bt_b1a  = (unsigned short*)alB((size_t)2 * 27 * 32 * 32 * 2);
    unsigned short* Bt_b1b  = (unsigned short*)alB((size_t)27 * 32 * 32 * 2);
    unsigned short* Bt_pa   = (unsigned short*)alB((size_t)27 * 16 * 32 * 2);

    size_t fixed = (off + 255) & ~(size_t)255;
    size_t per_block = (U1 + U2 + U3) * 2 + 768;
    size_t avail = ws_size > fixed ? ws_size - fixed : 0;
    int NB = (int)(avail / per_block);
    if (NB > 27) NB = 27;
    if (NB < 1) NB = 1;

    unsigned short* buf1 = (unsigned short*)alB((size_t)NB * U1 * 2);
    unsigned short* buf2 = (unsigned short*)alB((size_t)NB * U2 * 2);
    unsigned short* buf3 = (unsigned short*)alB((size_t)NB * U3 * 2);

    // weight prep + prev transpose (tiny, once)
    k_tr_conv<<<cdiv(1 * 16 * 27, 256), 256, 0, stream>>>(w_ts1, wT_ts1, 1, 16);
    k_tr_conv<<<cdiv(16 * 8 * 27, 256), 256, 0, stream>>>(w_pb, wT_pb, 16, 8);
    k_trwT<<<cdiv(64 * 32 * 32, 256), 256, 0, stream>>>(w_upt, BtT_upt);
    k_trw<<<cdiv(1 * 27 * 32 * 32, 256), 256, 0, stream>>>(w_upc, Bt_upc, 32, 1, 32);
    k_trw<<<cdiv(1 * 27 * 16 * 32, 256), 256, 0, stream>>>(w_ts2, Bt_ts2, 16, 1, 16);
    k_trw<<<cdiv(2 * 27 * 32 * 32, 256), 256, 0, stream>>>(w_b1a, Bt_b1a, 48, 2, 32);
    k_trw<<<cdiv(1 * 27 * 32 * 32, 256), 256, 0, stream>>>(w_b1b, Bt_b1b, 32, 1, 32);
    k_trw<<<cdiv(1 * 27 * 16 * 32, 256), 256, 0, stream>>>(w_pa, Bt_pa, 32, 1, 16);
    k_tprev<<<dim3(64, 27), 256, 0, stream>>>(prev, prevT);

    for (int n0 = 0; n0 < 27; n0 += NB) {
        int nc = 27 - n0 < NB ? 27 - n0 : NB;

        // producers into buf1 [34^3][48]
        k_cT<<<dim3(17 * 5, 8, nc), 192, 0, stream>>>(prevT, BtT_upt, buf1, n0);
        k_ts1<<<dim3(cdiv(39304, 256), nc), 256, 0, stream>>>(tsdf, wT_ts1, buf1, n0);

        // upc: buf1 c0..31 -> buf2 c0..31 ; ts2: buf1 c32..47 -> buf2 c32..47
        k_cm<32, 48, 0, 1, 32, 48, 0, 34, 32, false, false, 4>
            <<<dim3(32 * 8, nc), 256, 0, stream>>>(buf1, Bt_upc, buf2, U1, U2);
        k_cm<16, 48, 32, 1, 16, 48, 32, 34, 32, false, false, 4>
            <<<dim3(32 * 8, nc), 256, 0, stream>>>(buf1, Bt_ts2, buf2, U1, U2);

        // b1a: buf2 (48ch, pad+relu) -> buf3 [34^3][32]
        k_cm<48, 48, 0, 2, 32, 32, 0, 32, 34, true, true, 5>
            <<<dim3(34 * 9, nc), 320, 0, stream>>>(buf2, Bt_b1a, buf3, U2, U3);

        // b1b: buf3 -> feat in buf1 region [32^3][32]
        k_cm<32, 32, 0, 1, 32, 32, 0, 34, 32, false, false, 4>
            <<<dim3(32 * 8, nc), 256, 0, stream>>>(buf3, Bt_b1b, buf1, U3, U1);

        // pa: feat -> buf2 region [30^3][16], relu
        k_cm<32, 32, 0, 1, 16, 16, 0, 32, 30, false, true, 4>
            <<<dim3(30 * 8, nc), 256, 0, stream>>>(buf1, Bt_pa, buf2, U1, U2);

        // pool3 into global P1 (fp32 NCDHW)
        k_pool3<<<cdiv(nc * 16000, 256), 256, 0, stream>>>(buf2, P1, n0, nc);
    }

    // tail
    k_conv3<16, 8, 10, 8><<<dim3(cdiv(512, 256), 27), 256, 0, stream>>>(P1, wT_pb, P2);
    k_final<<<27, 64, 0, stream>>>(P2, w_lin, b_lin, dout);
}